// Round 3
// baseline (337.177 us; speedup 1.0000x reference)
//
#include <hip/hip_runtime.h>
#include <hip/hip_bf16.h>
#include <hip/hip_cooperative_groups.h>
#include <math.h>

namespace cg = cooperative_groups;

#define H 1024
#define V 50257
#define L 10

#define NBLK 512
#define TPB  256
#define RPC  16                        // rows per chunk (4 waves x 4 rows)
#define NCHUNK ((V + RPC - 1) / RPC)   // 3142

// ---------------- Workspace layout (floats) ----------------
#define WS_CONCAT 0        // 2048: [embedded | attn_applied]
#define WS_X      2048     // 1024
#define WS_GH     3072     // 3072
#define WS_HNEW   6144     // 1024
#define WS_CTR    7168     // 1 int (dynamic chunk counter)
#define WS_LOGITS 8192     // V  -> ends 58449
#define WS_PAIRS  58496    // 2*NCHUNK = 6284 -> ends 64780 (~259 KB, same as R2)

__device__ __forceinline__ float wave_reduce(float a) {
    #pragma unroll
    for (int off = 32; off > 0; off >>= 1) a += __shfl_down(a, off);
    return a;
}

__device__ __forceinline__ void lse_merge(float& m, float& s, float pm, float ps) {
    if (pm == -INFINITY) return;
    if (m == -INFINITY)  { m = pm; s = ps; }
    else if (pm <= m)    { s += ps * expf(pm - m); }
    else                 { s = s * expf(m - pm) + ps; m = pm; }
}

__device__ __forceinline__ float dot4(float4 a, float4 x) {
    return a.x * x.x + a.y * x.y + a.z * x.z + a.w * x.w;
}

// =================== cooperative mega-kernel ===================
__global__ __launch_bounds__(TPB, 2) void mega(
    const int* __restrict__ idx, const float* __restrict__ hidden,
    const float* __restrict__ enc_outs, const float* __restrict__ emb,
    const float* __restrict__ attn_W, const float* __restrict__ attn_b,
    const float* __restrict__ comb_W, const float* __restrict__ comb_b,
    const float* __restrict__ W_ih, const float* __restrict__ W_hh,
    const float* __restrict__ b_ih, const float* __restrict__ b_hh,
    const float* __restrict__ out_W, const float* __restrict__ out_b,
    float* __restrict__ ws, float* __restrict__ out)
{
    cg::grid_group grid = cg::this_grid();
    const int b = blockIdx.x, t = threadIdx.x;
    const int wave = t >> 6, lane = t & 63;

    __shared__ float s_w[16];
    __shared__ float psm[4], pss[4];
    __shared__ int   s_c;
    __shared__ float rm[TPB], rs[TPB];

    float4 pf[16];   // prefetched chunk b of out_W: 16 rows, 64 KB/block

    // ---------------- P0: attn (blk 0) | gh (blk 1..192) | prefetch ----------------
    if (b >= 193) {          // idle blocks: prefetch immediately
        const int r0 = b * RPC + wave * 4;
        #pragma unroll
        for (int k = 0; k < 4; ++k) {
            const float4* w4 = (const float4*)(out_W + (size_t)(r0 + k) * H);
            #pragma unroll
            for (int j = 0; j < 4; ++j) pf[k * 4 + j] = w4[lane + 64 * j];
        }
    }

    if (b == 0) {
        if (t == 0) *(int*)(ws + WS_CTR) = NBLK;   // reset dynamic counter每 call
        const float* erow = emb + (size_t)idx[0] * H;
        for (int i = t; i < H; i += TPB) ws[WS_CONCAT + i] = erow[i];
        const float4* e4 = (const float4*)erow;
        const float4* h4 = (const float4*)hidden;
        for (int l = wave; l < L; l += 4) {
            const float4* w4 = (const float4*)(attn_W + (size_t)l * 2 * H);
            float acc = 0.f;
            #pragma unroll
            for (int ii = 0; ii < 8; ++ii) {
                const int i = lane + 64 * ii;
                const float4 a = w4[i];
                const float4 x = (i < 256) ? e4[i] : h4[i - 256];
                acc += dot4(a, x);
            }
            acc = wave_reduce(acc);
            if (lane == 0) s_w[l] = acc + attn_b[l];
        }
        __syncthreads();
        if (t == 0) {
            float m = -1e30f;
            #pragma unroll
            for (int l = 0; l < L; ++l) m = fmaxf(m, s_w[l]);
            float s = 0.f;
            #pragma unroll
            for (int l = 0; l < L; ++l) { s_w[l] = expf(s_w[l] - m); s += s_w[l]; }
            const float inv = 1.f / s;
            #pragma unroll
            for (int l = 0; l < L; ++l) s_w[l] *= inv;
        }
        __syncthreads();
        if (t < L) out[V + H + t] = s_w[t];
        for (int i = t; i < H; i += TPB) {
            float acc = 0.f;
            #pragma unroll
            for (int l = 0; l < L; ++l) acc += s_w[l] * enc_outs[l * H + i];
            ws[WS_CONCAT + H + i] = acc;
        }
    } else if (b <= 192) {
        const int r0 = (b - 1) * RPC + wave * 4;
        const float4* v4 = (const float4*)hidden;
        float4 hx[4];
        #pragma unroll
        for (int j = 0; j < 4; ++j) hx[j] = v4[lane + 64 * j];
        #pragma unroll
        for (int k = 0; k < 4; ++k) {
            const int row = r0 + k;
            const float4* w4 = (const float4*)(W_hh + (size_t)row * H);
            float acc = 0.f;
            #pragma unroll
            for (int j = 0; j < 4; ++j) acc += dot4(w4[lane + 64 * j], hx[j]);
            acc = wave_reduce(acc);
            if (lane == 0) ws[WS_GH + row] = acc + b_hh[row];
        }
    }

    if (b < 193) {           // busy blocks: prefetch after their P0 work
        const int r0 = b * RPC + wave * 4;
        #pragma unroll
        for (int k = 0; k < 4; ++k) {
            const float4* w4 = (const float4*)(out_W + (size_t)(r0 + k) * H);
            #pragma unroll
            for (int j = 0; j < 4; ++j) pf[k * 4 + j] = w4[lane + 64 * j];
        }
    }

    grid.sync();

    // ---------------- P1: x = relu(comb_W @ concat + comb_b)  (blk 320..383) ----------------
    if (b >= 320 && b < 384) {
        const int r0 = (b - 320) * RPC + wave * 4;
        const float4* v4 = (const float4*)(ws + WS_CONCAT);
        float4 cx[8];
        #pragma unroll
        for (int j = 0; j < 8; ++j) cx[j] = v4[lane + 64 * j];
        #pragma unroll
        for (int k = 0; k < 4; ++k) {
            const int row = r0 + k;
            const float4* w4 = (const float4*)(comb_W + (size_t)row * 2 * H);
            float acc = 0.f;
            #pragma unroll
            for (int j = 0; j < 8; ++j) acc += dot4(w4[lane + 64 * j], cx[j]);
            acc = wave_reduce(acc);
            if (lane == 0) ws[WS_X + row] = fmaxf(acc + comb_b[row], 0.f);
        }
    }
    grid.sync();

    // ---------------- P2: gi + GRU pointwise  (blk 384..447) ----------------
    if (b >= 384 && b < 448) {
        const int u0 = (b - 384) * RPC + wave * 4;
        const float4* x4 = (const float4*)(ws + WS_X);
        float4 xx[4];
        #pragma unroll
        for (int j = 0; j < 4; ++j) xx[j] = x4[lane + 64 * j];
        #pragma unroll
        for (int k = 0; k < 4; ++k) {
            const int u = u0 + k;
            const float4* w0 = (const float4*)(W_ih + (size_t)u * H);
            const float4* w1 = (const float4*)(W_ih + (size_t)(H + u) * H);
            const float4* w2 = (const float4*)(W_ih + (size_t)(2 * H + u) * H);
            float a0 = 0.f, a1 = 0.f, a2 = 0.f;
            #pragma unroll
            for (int j = 0; j < 4; ++j) {
                const float4 x = xx[j];
                a0 += dot4(w0[lane + 64 * j], x);
                a1 += dot4(w1[lane + 64 * j], x);
                a2 += dot4(w2[lane + 64 * j], x);
            }
            a0 = wave_reduce(a0); a1 = wave_reduce(a1); a2 = wave_reduce(a2);
            if (lane == 0) {
                const float ir  = a0 + b_ih[u];
                const float iz  = a1 + b_ih[H + u];
                const float in_ = a2 + b_ih[2 * H + u];
                const float hr = ws[WS_GH + u];
                const float hz = ws[WS_GH + H + u];
                const float hn = ws[WS_GH + 2 * H + u];
                const float r = 1.f / (1.f + expf(-(ir + hr)));
                const float z = 1.f / (1.f + expf(-(iz + hz)));
                const float n = tanhf(in_ + r * hn);
                const float h = (1.f - z) * n + z * hidden[u];
                ws[WS_HNEW + u] = h;
                out[V + u] = h;
            }
        }
    }
    grid.sync();

    // ---------------- P3: logits = out_W @ h_new + out_b, per-chunk LSE pairs ----------------
    {
        int* ctr = (int*)(ws + WS_CTR);
        const float4* h4 = (const float4*)(ws + WS_HNEW);
        float4 hx[4];
        #pragma unroll
        for (int j = 0; j < 4; ++j) hx[j] = h4[lane + 64 * j];

        int c = b;          // static first chunk (prefetched)
        bool first = true;
        while (c < NCHUNK) {
            const int rbase = c * RPC + wave * 4;
            float wm = -INFINITY, wsum = 0.f;
            #pragma unroll
            for (int k = 0; k < 4; ++k) {
                const int row = rbase + k;
                if (row < V) {
                    float acc = 0.f;
                    if (first) {
                        #pragma unroll
                        for (int j = 0; j < 4; ++j) acc += dot4(pf[k * 4 + j], hx[j]);
                    } else {
                        const float4* w4 = (const float4*)(out_W + (size_t)row * H);
                        #pragma unroll
                        for (int j = 0; j < 4; ++j) acc += dot4(w4[lane + 64 * j], hx[j]);
                    }
                    acc = wave_reduce(acc);
                    if (lane == 0) {
                        const float val = acc + out_b[row];
                        ws[WS_LOGITS + row] = val;
                        lse_merge(wm, wsum, val, 1.f);
                    }
                }
            }
            if (lane == 0) { psm[wave] = wm; pss[wave] = wsum; }
            if (t == 0) s_c = atomicAdd(ctr, 1);
            __syncthreads();
            if (t == 0) {
                float m = -INFINITY, s = 0.f;
                #pragma unroll
                for (int w = 0; w < 4; ++w) lse_merge(m, s, psm[w], pss[w]);
                ws[WS_PAIRS + 2 * c]     = m;
                ws[WS_PAIRS + 2 * c + 1] = s;
            }
            const int cn = s_c;
            __syncthreads();
            c = cn;
            first = false;
        }
    }
    grid.sync();

    // ---------------- P4: redundant pair merge + write log-softmax ----------------
    {
        float m = -INFINITY, s = 0.f;
        for (int i = t; i < NCHUNK; i += TPB)
            lse_merge(m, s, ws[WS_PAIRS + 2 * i], ws[WS_PAIRS + 2 * i + 1]);
        rm[t] = m; rs[t] = s;
        __syncthreads();
        for (int k = TPB / 2; k > 0; k >>= 1) {
            if (t < k) {
                float mm = rm[t], ssv = rs[t];
                lse_merge(mm, ssv, rm[t + k], rs[t + k]);
                rm[t] = mm; rs[t] = ssv;
            }
            __syncthreads();
        }
        const float M  = rm[0];
        const float LS = logf(rs[0]);
        const int g = b * TPB + t;
        if (g < V) out[g] = ws[WS_LOGITS + g] - M - LS;
    }
}

// =================== fallback path (R2 kernels, launched only if coop launch fails) ===================
__global__ void k_attn(const int* __restrict__ idx, const float* __restrict__ hidden,
                       const float* __restrict__ enc_outs, const float* __restrict__ emb,
                       const float* __restrict__ attn_W, const float* __restrict__ attn_b,
                       float* __restrict__ ws, float* __restrict__ attnw_out) {
    __shared__ float s_w[16];
    const int t = threadIdx.x, wave = t >> 6, lane = t & 63;
    const float* erow = emb + (size_t)idx[0] * H;
    for (int i = t; i < H; i += 640) ws[WS_CONCAT + i] = erow[i];
    if (wave < L) {
        const float4* w4 = (const float4*)(attn_W + (size_t)wave * 2 * H);
        const float4* e4 = (const float4*)erow;
        const float4* h4 = (const float4*)hidden;
        float acc = 0.f;
        #pragma unroll
        for (int i = lane; i < 512; i += 64) {
            const float4 a = w4[i];
            const float4 x = (i < 256) ? e4[i] : h4[i - 256];
            acc += dot4(a, x);
        }
        acc = wave_reduce(acc);
        if (lane == 0) s_w[wave] = acc + attn_b[wave];
    }
    __syncthreads();
    if (t == 0) {
        float m = -1e30f;
        for (int l = 0; l < L; ++l) m = fmaxf(m, s_w[l]);
        float s = 0.f;
        for (int l = 0; l < L; ++l) { s_w[l] = expf(s_w[l] - m); s += s_w[l]; }
        const float inv = 1.f / s;
        for (int l = 0; l < L; ++l) s_w[l] *= inv;
    }
    __syncthreads();
    if (t < L) attnw_out[t] = s_w[t];
    for (int i = t; i < H; i += 640) {
        float acc = 0.f;
        #pragma unroll
        for (int l = 0; l < L; ++l) acc += s_w[l] * enc_outs[l * H + i];
        ws[WS_CONCAT + H + i] = acc;
    }
}

__global__ void k_comb_gh(const float* __restrict__ comb_W, const float* __restrict__ comb_b,
                          const float* __restrict__ W_hh, const float* __restrict__ b_hh,
                          const float* __restrict__ hidden, float* __restrict__ ws) {
    const int wave = threadIdx.x >> 6, lane = threadIdx.x & 63;
    if (blockIdx.x < 256) {
        const int row = blockIdx.x * 4 + wave;
        const float4* w4 = (const float4*)(comb_W + (size_t)row * 2 * H);
        const float4* v4 = (const float4*)(ws + WS_CONCAT);
        float acc = 0.f;
        #pragma unroll
        for (int i = lane; i < 512; i += 64) acc += dot4(w4[i], v4[i]);
        acc = wave_reduce(acc);
        if (lane == 0) ws[WS_X + row] = fmaxf(acc + comb_b[row], 0.f);
    } else {
        const int row = (blockIdx.x - 256) * 4 + wave;
        const float4* w4 = (const float4*)(W_hh + (size_t)row * H);
        const float4* v4 = (const float4*)hidden;
        float acc = 0.f;
        #pragma unroll
        for (int i = lane; i < 256; i += 64) acc += dot4(w4[i], v4[i]);
        acc = wave_reduce(acc);
        if (lane == 0) ws[WS_GH + row] = acc + b_hh[row];
    }
}

__global__ void k_gi_gru(const float* __restrict__ W_ih, const float* __restrict__ b_ih,
                         const float* __restrict__ hidden, float* __restrict__ ws,
                         float* __restrict__ h_out) {
    const int wave = threadIdx.x >> 6, lane = threadIdx.x & 63;
    const int j = blockIdx.x * 16 + wave;
    const float4* xv = (const float4*)(ws + WS_X);
    const float4* w0 = (const float4*)(W_ih + (size_t)j * H);
    const float4* w1 = (const float4*)(W_ih + (size_t)(H + j) * H);
    const float4* w2 = (const float4*)(W_ih + (size_t)(2 * H + j) * H);
    float a0 = 0.f, a1 = 0.f, a2 = 0.f;
    #pragma unroll
    for (int i = lane; i < 256; i += 64) {
        const float4 x = xv[i];
        a0 += dot4(w0[i], x); a1 += dot4(w1[i], x); a2 += dot4(w2[i], x);
    }
    a0 = wave_reduce(a0); a1 = wave_reduce(a1); a2 = wave_reduce(a2);
    if (lane == 0) {
        const float ir = a0 + b_ih[j], iz = a1 + b_ih[H + j], in_ = a2 + b_ih[2 * H + j];
        const float hr = ws[WS_GH + j], hz = ws[WS_GH + H + j], hn = ws[WS_GH + 2 * H + j];
        const float r = 1.f / (1.f + expf(-(ir + hr)));
        const float z = 1.f / (1.f + expf(-(iz + hz)));
        const float n = tanhf(in_ + r * hn);
        const float h = (1.f - z) * n + z * hidden[j];
        ws[WS_HNEW + j] = h;
        h_out[j] = h;
    }
}

__global__ void k_out_mv(const float* __restrict__ out_W, const float* __restrict__ out_b,
                         const float* __restrict__ ws_in, float* __restrict__ logits,
                         float* __restrict__ pairs) {
    __shared__ float sm[4], ss[4];
    const int wave = threadIdx.x >> 6, lane = threadIdx.x & 63;
    const int base = blockIdx.x * RPC + wave * 4;
    const float4* v4 = (const float4*)(ws_in + WS_HNEW);
    float wm = -INFINITY, wsum = 0.f;
    #pragma unroll
    for (int k = 0; k < 4; ++k) {
        const int row = base + k;
        if (row >= V) break;
        const float4* w4 = (const float4*)(out_W + (size_t)row * H);
        float acc = 0.f;
        #pragma unroll
        for (int i = lane; i < 256; i += 64) acc += dot4(w4[i], v4[i]);
        acc = wave_reduce(acc);
        if (lane == 0) {
            const float val = acc + out_b[row];
            logits[row] = val;
            lse_merge(wm, wsum, val, 1.f);
        }
    }
    if (lane == 0) { sm[wave] = wm; ss[wave] = wsum; }
    __syncthreads();
    if (threadIdx.x == 0) {
        float m = -INFINITY, s = 0.f;
        #pragma unroll
        for (int w = 0; w < 4; ++w) lse_merge(m, s, sm[w], ss[w]);
        pairs[2 * blockIdx.x] = m; pairs[2 * blockIdx.x + 1] = s;
    }
}

__global__ void k_write(const float* __restrict__ logits, const float* __restrict__ pairs,
                        float* __restrict__ out) {
    __shared__ float sm[256], ss[256];
    const int t = threadIdx.x;
    float m = -INFINITY, s = 0.f;
    for (int i = t; i < NCHUNK; i += 256) lse_merge(m, s, pairs[2 * i], pairs[2 * i + 1]);
    sm[t] = m; ss[t] = s; __syncthreads();
    for (int k = 128; k > 0; k >>= 1) {
        if (t < k) {
            float mm = sm[t], ssv = ss[t];
            lse_merge(mm, ssv, sm[t + k], ss[t + k]);
            sm[t] = mm; ss[t] = ssv;
        }
        __syncthreads();
    }
    const float M = sm[0], LS = logf(ss[0]);
    const int i = blockIdx.x * 256 + t;
    if (i < V) out[i] = logits[i] - M - LS;
}

extern "C" void kernel_launch(void* const* d_in, const int* in_sizes, int n_in,
                              void* d_out, int out_size, void* d_ws, size_t ws_size,
                              hipStream_t stream) {
    const int*   idx      = (const int*)  d_in[0];
    const float* hidden   = (const float*)d_in[1];
    const float* enc_outs = (const float*)d_in[3];
    const float* emb      = (const float*)d_in[4];
    const float* attn_W   = (const float*)d_in[5];
    const float* attn_b   = (const float*)d_in[6];
    const float* comb_W   = (const float*)d_in[7];
    const float* comb_b   = (const float*)d_in[8];
    const float* W_ih     = (const float*)d_in[9];
    const float* W_hh     = (const float*)d_in[10];
    const float* b_ih     = (const float*)d_in[11];
    const float* b_hh     = (const float*)d_in[12];
    const float* out_W    = (const float*)d_in[13];
    const float* out_b    = (const float*)d_in[14];

    float* ws  = (float*)d_ws;
    float* out = (float*)d_out;   // [0,V) log-probs | [V,V+H) h_new | [V+H,+L) attn_w

    void* args[] = { (void*)&idx, (void*)&hidden, (void*)&enc_outs, (void*)&emb,
                     (void*)&attn_W, (void*)&attn_b, (void*)&comb_W, (void*)&comb_b,
                     (void*)&W_ih, (void*)&W_hh, (void*)&b_ih, (void*)&b_hh,
                     (void*)&out_W, (void*)&out_b, (void*)&ws, (void*)&out };

    hipError_t err = hipLaunchCooperativeKernel((const void*)mega, dim3(NBLK), dim3(TPB),
                                                args, 0, stream);
    if (err != hipSuccess) {
        // fallback: R2 five-kernel path
        k_attn<<<1, 640, 0, stream>>>(idx, hidden, enc_outs, emb, attn_W, attn_b,
                                      ws, out + V + H);
        k_comb_gh<<<1024, 256, 0, stream>>>(comb_W, comb_b, W_hh, b_hh, hidden, ws);
        k_gi_gru<<<64, 1024, 0, stream>>>(W_ih, b_ih, hidden, ws, out + V);
        k_out_mv<<<NCHUNK, 256, 0, stream>>>(out_W, out_b, ws,
                                             ws + WS_LOGITS, ws + WS_PAIRS);
        k_write<<<(V + 255) / 256, 256, 0, stream>>>(ws + WS_LOGITS, ws + WS_PAIRS, out);
    }
}

// Round 4
// 59.502 us; speedup vs baseline: 5.6667x; 5.6667x over previous
//
#include <hip/hip_runtime.h>
#include <hip/hip_bf16.h>
#include <math.h>

#define H 1024
#define V 50257
#define L 10

#define RPC 16                         // rows per chunk in out_mv
#define NCHUNK ((V + RPC - 1) / RPC)   // 3142

// ---------------- Workspace layout (floats) ----------------
#define WS_AW     0        // 16   attn weights
#define WS_GH     16       // 3072 W_hh @ h0 + b_hh
#define WS_HALF1  3104     // 1024 comb_W[:, :H] @ embedded   (no bias)
#define WS_M2T    4128     // 10*1024, layout [l][r]
#define WS_HNEW   14368    // 1024
#define WS_LOGITS 15392    // V
#define WS_PAIRS  65664    // 2*NCHUNK

__device__ __forceinline__ float wave_reduce(float a) {
    #pragma unroll
    for (int off = 32; off > 0; off >>= 1) a += __shfl_down(a, off);
    return a;
}

__device__ __forceinline__ void lse_merge(float& m, float& s, float pm, float ps) {
    if (pm == -INFINITY) return;
    if (m == -INFINITY)  { m = pm; s = ps; }
    else if (pm <= m)    { s += ps * expf(pm - m); }
    else                 { s = s * expf(m - pm) + ps; m = pm; }
}

__device__ __forceinline__ float dot4(float4 a, float4 x) {
    return a.x * x.x + a.y * x.y + a.z * x.z + a.w * x.w;
}

// ========== K1: attn softmax | gh | half1 | M2  (513 blocks x 256) ==========
// b==0      : attention logits + softmax -> ws[WS_AW], out tail
// b 1..192  : gh rows (16/block, 3072 rows)
// b 193..256: half1 rows (16/block, 1024 rows)
// b 257..512: M2 rows (4/block = 1/wave, 1024 rows)
__global__ __launch_bounds__(256) void k_stage1(
    const int* __restrict__ idx, const float* __restrict__ hidden,
    const float* __restrict__ enc_outs, const float* __restrict__ emb,
    const float* __restrict__ attn_W, const float* __restrict__ attn_b,
    const float* __restrict__ W_hh, const float* __restrict__ b_hh,
    const float* __restrict__ comb_W,
    float* __restrict__ ws, float* __restrict__ aw_out)
{
    const int b = blockIdx.x, t = threadIdx.x;
    const int wave = t >> 6, lane = t & 63;
    const float* erow = emb + (size_t)idx[0] * H;

    if (b == 0) {
        __shared__ float s_w[16];
        const float4* e4 = (const float4*)erow;
        const float4* h4 = (const float4*)hidden;
        for (int l = wave; l < L; l += 4) {
            const float4* w4 = (const float4*)(attn_W + (size_t)l * 2 * H);
            float acc = 0.f;
            #pragma unroll
            for (int ii = 0; ii < 8; ++ii) {
                const int i = lane + 64 * ii;
                const float4 a = w4[i];
                const float4 x = (i < 256) ? e4[i] : h4[i - 256];
                acc += dot4(a, x);
            }
            acc = wave_reduce(acc);
            if (lane == 0) s_w[l] = acc + attn_b[l];
        }
        __syncthreads();
        if (t == 0) {
            float m = -1e30f;
            #pragma unroll
            for (int l = 0; l < L; ++l) m = fmaxf(m, s_w[l]);
            float s = 0.f;
            #pragma unroll
            for (int l = 0; l < L; ++l) { s_w[l] = expf(s_w[l] - m); s += s_w[l]; }
            const float inv = 1.f / s;
            #pragma unroll
            for (int l = 0; l < L; ++l) s_w[l] *= inv;
        }
        __syncthreads();
        if (t < L) { ws[WS_AW + t] = s_w[t]; aw_out[t] = s_w[t]; }
    } else if (b <= 192) {
        // gh = W_hh @ h0 + b_hh
        const int r0 = (b - 1) * 16 + wave * 4;
        const float4* v4 = (const float4*)hidden;
        float4 hx[4];
        #pragma unroll
        for (int j = 0; j < 4; ++j) hx[j] = v4[lane + 64 * j];
        #pragma unroll
        for (int k = 0; k < 4; ++k) {
            const int row = r0 + k;
            const float4* w4 = (const float4*)(W_hh + (size_t)row * H);
            float acc = 0.f;
            #pragma unroll
            for (int j = 0; j < 4; ++j) acc += dot4(w4[lane + 64 * j], hx[j]);
            acc = wave_reduce(acc);
            if (lane == 0) ws[WS_GH + row] = acc + b_hh[row];
        }
    } else if (b <= 256) {
        // half1 = comb_W[:, :H] @ embedded  (no bias yet)
        const int r0 = (b - 193) * 16 + wave * 4;
        const float4* e4 = (const float4*)erow;
        float4 ex[4];
        #pragma unroll
        for (int j = 0; j < 4; ++j) ex[j] = e4[lane + 64 * j];
        #pragma unroll
        for (int k = 0; k < 4; ++k) {
            const int row = r0 + k;
            const float4* w4 = (const float4*)(comb_W + (size_t)row * 2 * H);
            float acc = 0.f;
            #pragma unroll
            for (int j = 0; j < 4; ++j) acc += dot4(w4[lane + 64 * j], ex[j]);
            acc = wave_reduce(acc);
            if (lane == 0) ws[WS_HALF1 + row] = acc;
        }
    } else {
        // M2T[l][r] = dot(comb_W[r, H:2H], enc_outs[l]),  one row r per wave
        const int r = (b - 257) * 4 + wave;
        const float4* w4 = (const float4*)(comb_W + (size_t)r * 2 * H + H);
        float acc[L];
        #pragma unroll
        for (int l = 0; l < L; ++l) acc[l] = 0.f;
        #pragma unroll
        for (int j = 0; j < 4; ++j) {
            const int i = lane + 64 * j;
            const float4 w = w4[i];
            #pragma unroll
            for (int l = 0; l < L; ++l) {
                const float4 e = ((const float4*)(enc_outs + l * H))[i];
                acc[l] += dot4(w, e);
            }
        }
        #pragma unroll
        for (int l = 0; l < L; ++l) {
            const float r_ = wave_reduce(acc[l]);
            if (lane == 0) ws[WS_M2T + l * 1024 + r] = r_;
        }
    }
}

// ========== K2: x (redundant per block) + gi + GRU  (64 blocks x 1024) ==========
__global__ __launch_bounds__(1024) void k_gi_gru(
    const float* __restrict__ W_ih, const float* __restrict__ b_ih,
    const float* __restrict__ comb_b, const float* __restrict__ hidden,
    float* __restrict__ ws, float* __restrict__ h_out)
{
    __shared__ float sx[1024];
    const int t = threadIdx.x;
    // phase a: x[t] = relu(half1[t] + comb_b[t] + sum_l M2T[l][t]*aw[l])
    {
        float acc = ws[WS_HALF1 + t] + comb_b[t];
        #pragma unroll
        for (int l = 0; l < L; ++l)
            acc += ws[WS_M2T + l * 1024 + t] * ws[WS_AW + l];
        sx[t] = fmaxf(acc, 0.f);
    }
    __syncthreads();
    // phase b: gi rows j, H+j, 2H+j ; GRU pointwise
    const int wave = t >> 6, lane = t & 63;
    const int j = blockIdx.x * 16 + wave;
    const float4* x4 = (const float4*)sx;
    float4 xx[4];
    #pragma unroll
    for (int q = 0; q < 4; ++q) xx[q] = x4[lane + 64 * q];
    const float4* w0 = (const float4*)(W_ih + (size_t)j * H);
    const float4* w1 = (const float4*)(W_ih + (size_t)(H + j) * H);
    const float4* w2 = (const float4*)(W_ih + (size_t)(2 * H + j) * H);
    float a0 = 0.f, a1 = 0.f, a2 = 0.f;
    #pragma unroll
    for (int q = 0; q < 4; ++q) {
        const int i = lane + 64 * q;
        a0 += dot4(w0[i], xx[q]);
        a1 += dot4(w1[i], xx[q]);
        a2 += dot4(w2[i], xx[q]);
    }
    a0 = wave_reduce(a0); a1 = wave_reduce(a1); a2 = wave_reduce(a2);
    if (lane == 0) {
        const float ir  = a0 + b_ih[j];
        const float iz  = a1 + b_ih[H + j];
        const float in_ = a2 + b_ih[2 * H + j];
        const float hr = ws[WS_GH + j];
        const float hz = ws[WS_GH + H + j];
        const float hn = ws[WS_GH + 2 * H + j];
        const float r = 1.f / (1.f + expf(-(ir + hr)));
        const float z = 1.f / (1.f + expf(-(iz + hz)));
        const float n = tanhf(in_ + r * hn);
        const float h = (1.f - z) * n + z * hidden[j];
        ws[WS_HNEW + j] = h;
        h_out[j] = h;
    }
}

// ========== K3: logits = out_W @ h_new + out_b + per-chunk LSE pairs ==========
__global__ __launch_bounds__(256) void k_out_mv(
    const float* __restrict__ out_W, const float* __restrict__ out_b,
    const float* __restrict__ ws_in, float* __restrict__ logits,
    float* __restrict__ pairs)
{
    __shared__ float sm[4], ss[4];
    const int wave = threadIdx.x >> 6, lane = threadIdx.x & 63;
    const int base = blockIdx.x * RPC + wave * 4;
    const float4* v4 = (const float4*)(ws_in + WS_HNEW);
    float4 hx[4];
    #pragma unroll
    for (int j = 0; j < 4; ++j) hx[j] = v4[lane + 64 * j];
    float wm = -INFINITY, wsum = 0.f;
    #pragma unroll
    for (int k = 0; k < 4; ++k) {
        const int row = base + k;
        if (row < V) {
            const float4* w4 = (const float4*)(out_W + (size_t)row * H);
            float acc = 0.f;
            #pragma unroll
            for (int j = 0; j < 4; ++j) acc += dot4(w4[lane + 64 * j], hx[j]);
            acc = wave_reduce(acc);
            if (lane == 0) {
                const float val = acc + out_b[row];
                logits[row] = val;
                lse_merge(wm, wsum, val, 1.f);
            }
        }
    }
    if (lane == 0) { sm[wave] = wm; ss[wave] = wsum; }
    __syncthreads();
    if (threadIdx.x == 0) {
        float m = -INFINITY, s = 0.f;
        #pragma unroll
        for (int w = 0; w < 4; ++w) lse_merge(m, s, sm[w], ss[w]);
        pairs[2 * blockIdx.x] = m; pairs[2 * blockIdx.x + 1] = s;
    }
}

// ========== K4: redundant pair merge + write log-softmax ==========
__global__ __launch_bounds__(256) void k_write(
    const float* __restrict__ logits, const float* __restrict__ pairs,
    float* __restrict__ out)
{
    __shared__ float sm[256], ss[256];
    const int t = threadIdx.x;
    float m = -INFINITY, s = 0.f;
    for (int i = t; i < NCHUNK; i += 256) lse_merge(m, s, pairs[2 * i], pairs[2 * i + 1]);
    sm[t] = m; ss[t] = s; __syncthreads();
    for (int k = 128; k > 0; k >>= 1) {
        if (t < k) {
            float mm = sm[t], ssv = ss[t];
            lse_merge(mm, ssv, sm[t + k], ss[t + k]);
            sm[t] = mm; ss[t] = ssv;
        }
        __syncthreads();
    }
    const float M = sm[0], LS = logf(ss[0]);
    const int i = blockIdx.x * 256 + t;
    if (i < V) out[i] = logits[i] - M - LS;
}

extern "C" void kernel_launch(void* const* d_in, const int* in_sizes, int n_in,
                              void* d_out, int out_size, void* d_ws, size_t ws_size,
                              hipStream_t stream) {
    const int*   idx      = (const int*)  d_in[0];
    const float* hidden   = (const float*)d_in[1];
    const float* enc_outs = (const float*)d_in[3];
    const float* emb      = (const float*)d_in[4];
    const float* attn_W   = (const float*)d_in[5];
    const float* attn_b   = (const float*)d_in[6];
    const float* comb_W   = (const float*)d_in[7];
    const float* comb_b   = (const float*)d_in[8];
    const float* W_ih     = (const float*)d_in[9];
    const float* W_hh     = (const float*)d_in[10];
    const float* b_ih     = (const float*)d_in[11];
    const float* b_hh     = (const float*)d_in[12];
    const float* out_W    = (const float*)d_in[13];
    const float* out_b    = (const float*)d_in[14];

    float* ws  = (float*)d_ws;
    float* out = (float*)d_out;   // [0,V) log-probs | [V,V+H) h_new | [V+H,+L) attn_w

    // K1: attn softmax | gh | half1 | M2   (all independent given inputs)
    k_stage1<<<513, 256, 0, stream>>>(idx, hidden, enc_outs, emb,
                                      attn_W, attn_b, W_hh, b_hh, comb_W,
                                      ws, out + V + H);
    // K2: x (redundant/block) + gi + GRU -> h_new
    k_gi_gru<<<64, 1024, 0, stream>>>(W_ih, b_ih, comb_b, hidden, ws, out + V);
    // K3: big matvec + per-chunk LSE pairs
    k_out_mv<<<NCHUNK, 256, 0, stream>>>(out_W, out_b, ws,
                                         ws + WS_LOGITS, ws + WS_PAIRS);
    // K4: merge pairs + write log-softmax
    k_write<<<(V + 255) / 256, 256, 0, stream>>>(ws + WS_LOGITS, ws + WS_PAIRS, out);
}